// Round 14
// baseline (7815.071 us; speedup 1.0000x reference)
//
#include <hip/hip_runtime.h>
#include <hip/hip_bf16.h>
#include <cstdint>
#include <cstddef>

#define DEV __device__ __forceinline__

typedef _Float16 h2v __attribute__((ext_vector_type(2)));
typedef unsigned u4v __attribute__((ext_vector_type(4)));

DEV float sigmoidf_(float x) { return 1.0f / (1.0f + __expf(-x)); }
DEV float tanhf_(float x) {
    float e = __expf(2.0f * x);
    return 1.0f - 2.0f / (e + 1.0f);
}
DEV h2v asH2(unsigned x) { union { unsigned u; h2v h; } c; c.u = x; return c.h; }

// Un-sinkable, un-rematerializable 16B load.
DEV u4v gload(const void* p) {
    u4v r;
    asm volatile("global_load_dwordx4 %0, %1, off\n\ts_waitcnt vmcnt(0)"
                 : "=v"(r) : "v"(p) : "memory");
    return r;
}

// LDS-only barrier: does NOT drain vmcnt; global prefetch/stores stay in flight.
#define LDS_BARRIER() asm volatile("s_waitcnt lgkmcnt(0)\n\ts_barrier" ::: "memory")

// ---------------------------------------------------------------------------
// Pack 10 matrices (256x64 each) to f16 pairs, split-K layout:
//   dst[m][half][qs][u][w]   (qs = q*4+s: gate q, slice s; w = word 0..3)
// m: 0-2 l1Whh, 3-5 l2Whh, 6-7 Wih12 (l1 layers 1,2), 8-9 l2Wih layers 1,2.
// ---------------------------------------------------------------------------
__global__ __launch_bounds__(256) void pack_w(
    const float* __restrict__ l1Whh, const float* __restrict__ l2Whh,
    const float* __restrict__ Wih12, const float* __restrict__ l2Wih,
    unsigned* __restrict__ wP)
{
    int idx = blockIdx.x * 256 + threadIdx.x;   // 10*8192 = 81920
    int m = idx >> 13;
    int rem = idx & 8191;
    int half = rem >> 12;
    int qs = (rem >> 8) & 15;
    int u = (rem >> 2) & 63;
    int w = rem & 3;
    int q = qs >> 2, s = qs & 3;
    int jp = 16 * half + 4 * s + w;

    const float* W;
    if (m < 3)      W = l1Whh + (size_t)m * 16384;
    else if (m < 6) W = l2Whh + (size_t)(m - 3) * 16384;
    else if (m < 8) W = Wih12 + (size_t)(m - 6) * 16384;
    else            W = l2Wih + (size_t)(m - 7) * 16384;   // layers 1,2

    const float* row = W + (size_t)(q * 64 + u) * 64;
    union { h2v h; unsigned u32; } c;
    c.h = (h2v){(_Float16)row[2 * jp], (_Float16)row[2 * jp + 1]};
    wP[idx] = c.u32;
}

// ---------------------------------------------------------------------------
// Input projection (layer 0 of each stack only): xg[b,t,u*4+q] unit-major.
// ---------------------------------------------------------------------------
__global__ __launch_bounds__(256) void proj_kernel(
    const float* __restrict__ x, const float* __restrict__ Wih,
    const float* __restrict__ bias, const float* __restrict__ gate,
    float* __restrict__ xg, int D, int T)
{
    __shared__ float xS[16 * 64];
    int tb = T / 16;
    int b  = blockIdx.x / tb;
    int t0 = (blockIdx.x % tb) * 16;
    int tid = threadIdx.x;

    int n = 16 * D;
    for (int e = tid; e < n; e += 256) {
        int t = e / D;
        int i = e - t * D;
        float v = x[((size_t)(b * T + t0 + t)) * D + i];
        if (gate) v += gate[b * T + t0 + t];
        xS[t * D + i] = v;
    }
    __syncthreads();

    int g = tid;
    float acc[16];
    float bg = bias[g];
#pragma unroll
    for (int t = 0; t < 16; t++) acc[t] = bg;

    const float* wr = Wih + (size_t)g * D;
    for (int i = 0; i < D; i++) {
        float w = wr[i];
#pragma unroll
        for (int t = 0; t < 16; t++) acc[t] += xS[t * D + i] * w;
    }

    float* og = xg + ((size_t)(b * T + t0)) * 256 + (g & 63) * 4 + (g >> 6);
#pragma unroll
    for (int t = 0; t < 16; t++) og[(size_t)t * 256] = acc[t];
}

// ---------------------------------------------------------------------------
// Pipelined 3-layer LSTM scan v14: ONE block per batch, SIX waves.
// Wave 2l+h: layer l, k-half h; per lane 16 (L0) or 32 (L1/L2) weight quads.
// THE FIX: amdgpu_waves_per_eu(1,2) -- a FEASIBLE range. With 6-wave
// workgroups + the 88KB LDS pad (1 wg/CU), achievable occupancy is exactly
// 1.5 waves/EU, which lies in [1,2]. R12's (3,3) and R13's (2,2) were
// unreachable (2.5/EU, 1.5/EU vs exact targets) -> backend ignored them ->
// 64-96-reg budget -> weights spilled to scratch and re-streamed every tick
// (~200 GB/s/CU = the whole 940ns tick). Budget 512/2=256 >= demand ~160.
// ---------------------------------------------------------------------------
__global__ __launch_bounds__(384)
__attribute__((amdgpu_waves_per_eu(1, 2)))
void scan3_kernel(
    const float* __restrict__ xg, const unsigned* __restrict__ whhP,
    const unsigned* __restrict__ wihP, const float* __restrict__ bvec,
    const float* __restrict__ h0, const float* __restrict__ c0,
    float* __restrict__ Hout, int T)
{
    __shared__ __align__(16) _Float16 hL[3][64];   // per-layer h (f16)
    __shared__ __align__(16) float4 exch[6][64];   // per-wave partials
    __shared__ float4 ldsPad[5120];                // 80KB: force 1 wg/CU
    int b = blockIdx.x;
    int tid = threadIdx.x;
    int wv = tid >> 6, u = tid & 63;
    if (T < 0) ((volatile float*)ldsPad)[u] = 0.f; // keep pad alive

    int layer = wv >> 1;
    int half  = wv & 1;
    bool isRed = (half == 0);

    // Whh half-slice: 16 quads via volatile-asm loads
    const u4v* wpH = (const u4v*)whhP + (size_t)layer * 2048 + (size_t)half * 1024 + u;
    u4v hI0 = gload(wpH + 0 * 64),  hI1 = gload(wpH + 1 * 64);
    u4v hI2 = gload(wpH + 2 * 64),  hI3 = gload(wpH + 3 * 64);
    u4v hF0 = gload(wpH + 4 * 64),  hF1 = gload(wpH + 5 * 64);
    u4v hF2 = gload(wpH + 6 * 64),  hF3 = gload(wpH + 7 * 64);
    u4v hG0 = gload(wpH + 8 * 64),  hG1 = gload(wpH + 9 * 64);
    u4v hG2 = gload(wpH + 10 * 64), hG3 = gload(wpH + 11 * 64);
    u4v hO0 = gload(wpH + 12 * 64), hO1 = gload(wpH + 13 * 64);
    u4v hO2 = gload(wpH + 14 * 64), hO3 = gload(wpH + 15 * 64);

    // Wih half-slice (layers 1,2 only)
    u4v z = {0u, 0u, 0u, 0u};
    u4v xI0 = z, xI1 = z, xI2 = z, xI3 = z, xF0 = z, xF1 = z, xF2 = z, xF3 = z;
    u4v xG0 = z, xG1 = z, xG2 = z, xG3 = z, xO0 = z, xO1 = z, xO2 = z, xO3 = z;
    if (layer > 0) {
        const u4v* wpX = (const u4v*)wihP + (size_t)(layer - 1) * 2048 + (size_t)half * 1024 + u;
        xI0 = gload(wpX + 0 * 64);  xI1 = gload(wpX + 1 * 64);
        xI2 = gload(wpX + 2 * 64);  xI3 = gload(wpX + 3 * 64);
        xF0 = gload(wpX + 4 * 64);  xF1 = gload(wpX + 5 * 64);
        xF2 = gload(wpX + 6 * 64);  xF3 = gload(wpX + 7 * 64);
        xG0 = gload(wpX + 8 * 64);  xG1 = gload(wpX + 9 * 64);
        xG2 = gload(wpX + 10 * 64); xG3 = gload(wpX + 11 * 64);
        xO0 = gload(wpX + 12 * 64); xO1 = gload(wpX + 13 * 64);
        xO2 = gload(wpX + 14 * 64); xO3 = gload(wpX + 15 * 64);
    }

    // reducer state: c, bias (L0 bias lives in xg)
    float c = 0.f;
    float4 bl = make_float4(0.f, 0.f, 0.f, 0.f);
    if (isRed) {
        c = c0[layer * 128 + b * 64 + u];
        hL[layer][u] = (_Float16)h0[layer * 128 + b * 64 + u];
        if (layer > 0) {
            const float* bb = bvec + layer * 256;
            bl = make_float4(bb[u], bb[64 + u], bb[128 + u], bb[192 + u]);
        }
    }
    __syncthreads();

    const u4v* hOwn   = (const u4v*)(&hL[layer][0]) + half * 4;
    const u4v* hBelow = (layer > 0) ? (const u4v*)(&hL[layer - 1][0]) + half * 4 : hOwn;

    // x preacts: wave 0 only, consume-then-reload 4-deep (R10 fix)
    const float4* xp = (const float4*)(xg + (size_t)b * T * 256) + u;
    float4 xb[4];
    xb[0] = xb[1] = xb[2] = xb[3] = make_float4(0.f, 0.f, 0.f, 0.f);
    if (wv == 0) {
#pragma unroll
        for (int k = 0; k < 4; k++) xb[k] = xp[(size_t)k * 64];
    }

    float* hout = Hout + (size_t)b * T * 64 + u;

#define FD(HP, WV, ACC) ACC = __builtin_amdgcn_fdot2(asH2(HP), asH2(WV), ACC, false)
#define QSTEP(HS, S, WI, WF, WG, WO) { u4v hp = (HS)[S];                      \
    FD(hp.x, WI.x, aI); FD(hp.y, WI.y, aI); FD(hp.z, WI.z, aI); FD(hp.w, WI.w, aI); \
    FD(hp.x, WF.x, aF); FD(hp.y, WF.y, aF); FD(hp.z, WF.z, aF); FD(hp.w, WF.w, aF); \
    FD(hp.x, WG.x, aG); FD(hp.y, WG.y, aG); FD(hp.z, WG.z, aG); FD(hp.w, WG.w, aG); \
    FD(hp.x, WO.x, aO); FD(hp.y, WO.y, aO); FD(hp.z, WO.z, aO); FD(hp.w, WO.w, aO); }

    int Tt = T + 4;   // pipeline drain
    for (int t4 = 0; t4 < Tt; t4 += 4) {
#pragma unroll
        for (int k = 0; k < 4; k++) {
            int tick = t4 + k;

            float aI, aF, aG, aO;
            if (wv == 0) {
                float4 x = xb[k];
                aI = x.x; aF = x.y; aG = x.z; aO = x.w;
                int tp = tick + 4; if (tp > T - 1) tp = T - 1;
                xb[k] = xp[(size_t)tp * 64];   // wait lands 4 ticks later
            } else {
                aI = aF = aG = aO = 0.f;
            }

            QSTEP(hOwn, 0, hI0, hF0, hG0, hO0)
            QSTEP(hOwn, 1, hI1, hF1, hG1, hO1)
            QSTEP(hOwn, 2, hI2, hF2, hG2, hO2)
            QSTEP(hOwn, 3, hI3, hF3, hG3, hO3)
            if (layer > 0) {
                QSTEP(hBelow, 0, xI0, xF0, xG0, xO0)
                QSTEP(hBelow, 1, xI1, xF1, xG1, xO1)
                QSTEP(hBelow, 2, xI2, xF2, xG2, xO2)
                QSTEP(hBelow, 3, xI3, xF3, xG3, xO3)
            }

            exch[wv][u] = make_float4(aI, aF, aG, aO);
            LDS_BARRIER();   // partials visible

            if (isRed) {
                int tcur = tick - layer;
                if ((unsigned)tcur < (unsigned)T) {
                    float4 p = exch[wv + 1][u];
                    float sI = aI + p.x + bl.x, sF = aF + p.y + bl.y;
                    float sG = aG + p.z + bl.z, sO = aO + p.w + bl.w;
                    c = sigmoidf_(sF) * c + sigmoidf_(sI) * tanhf_(sG);
                    float h = sigmoidf_(sO) * tanhf_(c);
                    hL[layer][u] = (_Float16)h;
                    if (layer == 2) hout[(size_t)tcur * 64] = h;
                }
            }
            LDS_BARRIER();   // h writes visible; WAR on exch protected
        }
    }
#undef FD
#undef QSTEP
}

// ---------------------------------------------------------------------------
// Hc[b, {max,mean,std(ddof=1)}, t] over hidden dim (64). One wave per (b,t).
// ---------------------------------------------------------------------------
__global__ __launch_bounds__(256) void stats_kernel(
    const float* __restrict__ H, float* __restrict__ Hc, int T)
{
    int wid = threadIdx.x >> 6, lane = threadIdx.x & 63;
    int bt = blockIdx.x * 4 + wid;
    int b = bt / T, t = bt - b * T;

    float x = H[(size_t)bt * 64 + lane];
    float mx = x, sm = x;
#pragma unroll
    for (int m = 32; m >= 1; m >>= 1) {
        mx = fmaxf(mx, __shfl_xor(mx, m));
        sm += __shfl_xor(sm, m);
    }
    float mean = sm * (1.0f / 64.0f);
    float d = x - mean;
    float ss = d * d;
#pragma unroll
    for (int m = 32; m >= 1; m >>= 1) ss += __shfl_xor(ss, m);
    float sd = sqrtf(ss * (1.0f / 63.0f));

    if (lane == 0) {
        float* o = Hc + (size_t)b * 3 * T;
        o[0 * T + t] = mx;
        o[1 * T + t] = mean;
        o[2 * T + t] = sd;
    }
}

// ---------------------------------------------------------------------------
// Middle conv/BN chain, single workgroup (1024 threads).
// ---------------------------------------------------------------------------
template <int CIN, int COUT, int MODE>
DEV void conv_bn_stage(const float* __restrict__ in, const float* __restrict__ w,
                       const float* __restrict__ bias, float* __restrict__ out,
                       float* __restrict__ gate, int T, int tid,
                       float* rs, float* rq, float* stm, float* sti)
{
    float lsum[COUT], lss[COUT];
#pragma unroll
    for (int oc = 0; oc < COUT; oc++) { lsum[oc] = 0.f; lss[oc] = 0.f; }

    for (int k = 0; k < 8; k++) {
        int p = tid + k * 1024;
        int b = p / T;
        int t = p - b * T;
        float acc[COUT];
#pragma unroll
        for (int oc = 0; oc < COUT; oc++) acc[oc] = bias[oc];
#pragma unroll
        for (int ic = 0; ic < CIN; ic++) {
            const float* row = in + ((size_t)b * CIN + ic) * T;
            float xv[11];
#pragma unroll
            for (int kk = 0; kk < 11; kk++) {
                int tt = t + kk - 5;
                xv[kk] = (tt >= 0 && tt < T) ? row[tt] : 0.f;
            }
#pragma unroll
            for (int oc = 0; oc < COUT; oc++) {
                const float* wr = w + ((size_t)oc * CIN + ic) * 11;
#pragma unroll
                for (int kk = 0; kk < 11; kk++) acc[oc] += xv[kk] * wr[kk];
            }
        }
#pragma unroll
        for (int oc = 0; oc < COUT; oc++) {
            out[((size_t)b * COUT + oc) * T + t] = acc[oc];
            lsum[oc] += acc[oc];
            lss[oc] += acc[oc] * acc[oc];
        }
    }
    __syncthreads();

    int lane = tid & 63, wid = tid >> 6;
#pragma unroll
    for (int oc = 0; oc < COUT; oc++) {
        float s = lsum[oc], qq = lss[oc];
#pragma unroll
        for (int m = 32; m >= 1; m >>= 1) {
            s += __shfl_xor(s, m);
            qq += __shfl_xor(qq, m);
        }
        if (lane == 0) { rs[wid] = s; rq[wid] = qq; }
        __syncthreads();
        if (tid == 0) {
            float S = 0.f, Q = 0.f;
            for (int i = 0; i < 16; i++) { S += rs[i]; Q += rq[i]; }
            float m_ = S / (float)(2 * T);
            float v = Q / (float)(2 * T) - m_ * m_;
            stm[oc] = m_;
            sti[oc] = rsqrtf(v + 1e-5f);
        }
        __syncthreads();
    }

    for (int k = 0; k < 8; k++) {
        int p = tid + k * 1024;
        int b = p / T;
        int t = p - b * T;
#pragma unroll
        for (int oc = 0; oc < COUT; oc++) {
            size_t idx = ((size_t)b * COUT + oc) * T + t;
            float v = (out[idx] - stm[oc]) * sti[oc];
            if (MODE == 0) out[idx] = fmaxf(v, 0.f);
            else           gate[p] = sigmoidf_(v);
        }
    }
    __syncthreads();
}

__global__ __launch_bounds__(1024) void middle_kernel(
    const float* __restrict__ Hc,
    const float* __restrict__ w1, const float* __restrict__ b1,
    const float* __restrict__ w2, const float* __restrict__ b2,
    const float* __restrict__ w3, const float* __restrict__ b3,
    const float* __restrict__ w4, const float* __restrict__ b4,
    float* __restrict__ bufA, float* __restrict__ bufB,
    float* __restrict__ gate, int T)
{
    __shared__ float rs[16], rq[16], stm[8], sti[8];
    int tid = threadIdx.x;
    conv_bn_stage<3, 3, 0>(Hc,   w1, b1, bufA, nullptr, T, tid, rs, rq, stm, sti);
    conv_bn_stage<3, 5, 0>(bufA, w2, b2, bufB, nullptr, T, tid, rs, rq, stm, sti);
    conv_bn_stage<5, 5, 0>(bufB, w3, b3, bufA, nullptr, T, tid, rs, rq, stm, sti);
    conv_bn_stage<5, 1, 1>(bufA, w4, b4, bufB, gate,    T, tid, rs, rq, stm, sti);
}

// ---------------------------------------------------------------------------
// Head: y = sigmoid(fc2(fc1(out2))). One wave per (b,t).
// ---------------------------------------------------------------------------
__global__ __launch_bounds__(256) void final_kernel(
    const float* __restrict__ out2, const float* __restrict__ fc1w,
    const float* __restrict__ fc1b, const float* __restrict__ fc2w,
    const float* __restrict__ fc2b, float* __restrict__ out, int T)
{
    int wid = threadIdx.x >> 6, lane = threadIdx.x & 63;
    int bt = blockIdx.x * 4 + wid;

    const float* o2 = out2 + (size_t)bt * 64;
    float acc = fc1b[lane];
    const float* wr = fc1w + (size_t)lane * 64;
#pragma unroll
    for (int k = 0; k < 64; k++) acc += o2[k] * wr[k];

    float p = acc * fc2w[lane];
#pragma unroll
    for (int m = 32; m >= 1; m >>= 1) p += __shfl_xor(p, m);

    if (lane == 0) out[bt] = sigmoidf_(p + fc2b[0]);
}

// ---------------------------------------------------------------------------
extern "C" void kernel_launch(void* const* d_in, const int* in_sizes, int n_in,
                              void* d_out, int out_size, void* d_ws, size_t ws_size,
                              hipStream_t stream)
{
    const float* data  = (const float*)d_in[0];
    const float* h01   = (const float*)d_in[1];
    const float* c01   = (const float*)d_in[2];
    const float* h02   = (const float*)d_in[3];
    const float* c02   = (const float*)d_in[4];
    const float* Wih0  = (const float*)d_in[5];
    const float* Wih12 = (const float*)d_in[6];
    const float* l1Whh = (const float*)d_in[7];
    const float* l1b   = (const float*)d_in[8];
    const float* l2Wih = (const float*)d_in[9];
    const float* l2Whh = (const float*)d_in[10];
    const float* l2b   = (const float*)d_in[11];
    const float* cw1 = (const float*)d_in[12]; const float* cb1 = (const float*)d_in[13];
    const float* cw2 = (const float*)d_in[14]; const float* cb2 = (const float*)d_in[15];
    const float* cw3 = (const float*)d_in[16]; const float* cb3 = (const float*)d_in[17];
    const float* cw4 = (const float*)d_in[18]; const float* cb4 = (const float*)d_in[19];
    const float* fc1w = (const float*)d_in[20]; const float* fc1b = (const float*)d_in[21];
    const float* fc2w = (const float*)d_in[22]; const float* fc2b = (const float*)d_in[23];
    float* out = (float*)d_out;

    const int T = in_sizes[0] / (2 * 40);   // 4096
    const int B = 2;

    float* ws   = (float*)d_ws;
    float* xg   = ws;                                // B*T*256
    float* seqA = xg   + (size_t)B * T * 256;        // B*T*64
    float* seqB = seqA + (size_t)B * T * 64;         // B*T*64
    float* Hc   = seqB + (size_t)B * T * 64;         // B*3*T
    float* bufA = Hc   + (size_t)B * 3 * T;          // B*5*T
    float* bufB = bufA + (size_t)B * 5 * T;          // B*5*T
    float* gate = bufB + (size_t)B * 5 * T;          // B*T
    unsigned* wP = (unsigned*)(gate + (size_t)B * T); // 10*8192 u32

    dim3 pg(B * (T / 16)), pb(256);

    pack_w<<<320, 256, 0, stream>>>(l1Whh, l2Whh, Wih12, l2Wih, wP);

    // ---- LSTM1: proj layer0 + pipelined 3-layer scan ----
    proj_kernel<<<pg, pb, 0, stream>>>(data, Wih0, l1b, nullptr, xg, 40, T);
    scan3_kernel<<<2, 384, 0, stream>>>(xg, wP, wP + 6 * 8192, l1b, h01, c01, seqA, T);

    // ---- temporal-attention gate ----
    stats_kernel<<<(2 * T) / 4, 256, 0, stream>>>(seqA, Hc, T);
    middle_kernel<<<1, 1024, 0, stream>>>(Hc, cw1, cb1, cw2, cb2, cw3, cb3, cw4, cb4,
                                          bufA, bufB, gate, T);

    // ---- LSTM2: proj layer0 (gate folded) + pipelined 3-layer scan ----
    proj_kernel<<<pg, pb, 0, stream>>>(seqA, l2Wih, l2b, gate, xg, 64, T);
    scan3_kernel<<<2, 384, 0, stream>>>(xg, wP + 3 * 8192, wP + 8 * 8192, l2b, h02, c02, seqB, T);

    // ---- head ----
    final_kernel<<<(2 * T) / 4, 256, 0, stream>>>(seqB, fc1w, fc1b, fc2w, fc2b, out, T);
}

// Round 15
// 7774.522 us; speedup vs baseline: 1.0052x; 1.0052x over previous
//
#include <hip/hip_runtime.h>
#include <hip/hip_bf16.h>
#include <cstdint>
#include <cstddef>

#define DEV __device__ __forceinline__

typedef _Float16 h2v __attribute__((ext_vector_type(2)));
typedef unsigned u4v __attribute__((ext_vector_type(4)));

DEV float sigmoidf_(float x) { return 1.0f / (1.0f + __expf(-x)); }
DEV float tanhf_(float x) {
    float e = __expf(2.0f * x);
    return 1.0f - 2.0f / (e + 1.0f);
}
DEV h2v asH2(unsigned x) { union { unsigned u; h2v h; } c; c.u = x; return c.h; }

// Un-sinkable, un-rematerializable 16B load.
DEV u4v gload(const void* p) {
    u4v r;
    asm volatile("global_load_dwordx4 %0, %1, off\n\ts_waitcnt vmcnt(0)"
                 : "=v"(r) : "v"(p) : "memory");
    return r;
}

// LDS-only barrier: does NOT drain vmcnt; global prefetch/stores stay in flight.
#define LDS_BARRIER() asm volatile("s_waitcnt lgkmcnt(0)\n\ts_barrier" ::: "memory")

// ---------------------------------------------------------------------------
// Pack 10 matrices (256x64 each) to f16 pairs, split-K layout:
//   dst[m][half][qs][u][w]   (qs = q*4+s: gate q, slice s; w = word 0..3)
// m: 0-2 l1Whh, 3-5 l2Whh, 6-7 Wih12 (l1 layers 1,2), 8-9 l2Wih layers 1,2.
// ---------------------------------------------------------------------------
__global__ __launch_bounds__(256) void pack_w(
    const float* __restrict__ l1Whh, const float* __restrict__ l2Whh,
    const float* __restrict__ Wih12, const float* __restrict__ l2Wih,
    unsigned* __restrict__ wP)
{
    int idx = blockIdx.x * 256 + threadIdx.x;   // 10*8192 = 81920
    int m = idx >> 13;
    int rem = idx & 8191;
    int half = rem >> 12;
    int qs = (rem >> 8) & 15;
    int u = (rem >> 2) & 63;
    int w = rem & 3;
    int q = qs >> 2, s = qs & 3;
    int jp = 16 * half + 4 * s + w;

    const float* W;
    if (m < 3)      W = l1Whh + (size_t)m * 16384;
    else if (m < 6) W = l2Whh + (size_t)(m - 3) * 16384;
    else if (m < 8) W = Wih12 + (size_t)(m - 6) * 16384;
    else            W = l2Wih + (size_t)(m - 7) * 16384;   // layers 1,2

    const float* row = W + (size_t)(q * 64 + u) * 64;
    union { h2v h; unsigned u32; } c;
    c.h = (h2v){(_Float16)row[2 * jp], (_Float16)row[2 * jp + 1]};
    wP[idx] = c.u32;
}

// ---------------------------------------------------------------------------
// Input projection (layer 0 of each stack only): xg[b,t,u*4+q] unit-major.
// ---------------------------------------------------------------------------
__global__ __launch_bounds__(256) void proj_kernel(
    const float* __restrict__ x, const float* __restrict__ Wih,
    const float* __restrict__ bias, const float* __restrict__ gate,
    float* __restrict__ xg, int D, int T)
{
    __shared__ float xS[16 * 64];
    int tb = T / 16;
    int b  = blockIdx.x / tb;
    int t0 = (blockIdx.x % tb) * 16;
    int tid = threadIdx.x;

    int n = 16 * D;
    for (int e = tid; e < n; e += 256) {
        int t = e / D;
        int i = e - t * D;
        float v = x[((size_t)(b * T + t0 + t)) * D + i];
        if (gate) v += gate[b * T + t0 + t];
        xS[t * D + i] = v;
    }
    __syncthreads();

    int g = tid;
    float acc[16];
    float bg = bias[g];
#pragma unroll
    for (int t = 0; t < 16; t++) acc[t] = bg;

    const float* wr = Wih + (size_t)g * D;
    for (int i = 0; i < D; i++) {
        float w = wr[i];
#pragma unroll
        for (int t = 0; t < 16; t++) acc[t] += xS[t * D + i] * w;
    }

    float* og = xg + ((size_t)(b * T + t0)) * 256 + (g & 63) * 4 + (g >> 6);
#pragma unroll
    for (int t = 0; t < 16; t++) og[(size_t)t * 256] = acc[t];
}

// ---------------------------------------------------------------------------
// Pipelined 3-layer LSTM scan v15: ONE block per batch, SIX waves.
// Wave 2l+h: layer l, k-half h; 16 (L0) or 32 (L1/L2) weight quads per lane.
// THE KNOB (last allocator attempt): __attribute__((amdgpu_num_vgpr(192))).
// In LLVM's getMaxNumVGPRs an explicit amdgpu-num-vgpr attribute overrides
// the occupancy-derived budget -- but is CLAMPED by amdgpu-waves-per-eu if
// present, so waves_per_eu is REMOVED here. 4 rounds of evidence: grant is
// waves-per-block-driven (2w->132, 6w->92, 10w->64) and waves_per_eu never
// moved it; the ~1000cyc/tick excess is spill-reload of the non-resident
// weights (demand ~160 vs grant 92). 192 >= demand -> zero spill.
// 2 waves/SIMD x 192 = 384 <= 512 HW pool.
// ---------------------------------------------------------------------------
__global__ __launch_bounds__(384)
__attribute__((amdgpu_num_vgpr(192)))
void scan3_kernel(
    const float* __restrict__ xg, const unsigned* __restrict__ whhP,
    const unsigned* __restrict__ wihP, const float* __restrict__ bvec,
    const float* __restrict__ h0, const float* __restrict__ c0,
    float* __restrict__ Hout, int T)
{
    __shared__ __align__(16) _Float16 hL[3][64];   // per-layer h (f16)
    __shared__ __align__(16) float4 exch[6][64];   // per-wave partials
    __shared__ float4 ldsPad[5120];                // 80KB: force 1 wg/CU
    int b = blockIdx.x;
    int tid = threadIdx.x;
    int wv = tid >> 6, u = tid & 63;
    if (T < 0) ((volatile float*)ldsPad)[u] = 0.f; // keep pad alive

    int layer = wv >> 1;
    int half  = wv & 1;
    bool isRed = (half == 0);

    // Whh half-slice: 16 quads via volatile-asm loads
    const u4v* wpH = (const u4v*)whhP + (size_t)layer * 2048 + (size_t)half * 1024 + u;
    u4v hI0 = gload(wpH + 0 * 64),  hI1 = gload(wpH + 1 * 64);
    u4v hI2 = gload(wpH + 2 * 64),  hI3 = gload(wpH + 3 * 64);
    u4v hF0 = gload(wpH + 4 * 64),  hF1 = gload(wpH + 5 * 64);
    u4v hF2 = gload(wpH + 6 * 64),  hF3 = gload(wpH + 7 * 64);
    u4v hG0 = gload(wpH + 8 * 64),  hG1 = gload(wpH + 9 * 64);
    u4v hG2 = gload(wpH + 10 * 64), hG3 = gload(wpH + 11 * 64);
    u4v hO0 = gload(wpH + 12 * 64), hO1 = gload(wpH + 13 * 64);
    u4v hO2 = gload(wpH + 14 * 64), hO3 = gload(wpH + 15 * 64);

    // Wih half-slice (layers 1,2 only)
    u4v z = {0u, 0u, 0u, 0u};
    u4v xI0 = z, xI1 = z, xI2 = z, xI3 = z, xF0 = z, xF1 = z, xF2 = z, xF3 = z;
    u4v xG0 = z, xG1 = z, xG2 = z, xG3 = z, xO0 = z, xO1 = z, xO2 = z, xO3 = z;
    if (layer > 0) {
        const u4v* wpX = (const u4v*)wihP + (size_t)(layer - 1) * 2048 + (size_t)half * 1024 + u;
        xI0 = gload(wpX + 0 * 64);  xI1 = gload(wpX + 1 * 64);
        xI2 = gload(wpX + 2 * 64);  xI3 = gload(wpX + 3 * 64);
        xF0 = gload(wpX + 4 * 64);  xF1 = gload(wpX + 5 * 64);
        xF2 = gload(wpX + 6 * 64);  xF3 = gload(wpX + 7 * 64);
        xG0 = gload(wpX + 8 * 64);  xG1 = gload(wpX + 9 * 64);
        xG2 = gload(wpX + 10 * 64); xG3 = gload(wpX + 11 * 64);
        xO0 = gload(wpX + 12 * 64); xO1 = gload(wpX + 13 * 64);
        xO2 = gload(wpX + 14 * 64); xO3 = gload(wpX + 15 * 64);
    }

    // reducer state: c, bias (L0 bias lives in xg)
    float c = 0.f;
    float4 bl = make_float4(0.f, 0.f, 0.f, 0.f);
    if (isRed) {
        c = c0[layer * 128 + b * 64 + u];
        hL[layer][u] = (_Float16)h0[layer * 128 + b * 64 + u];
        if (layer > 0) {
            const float* bb = bvec + layer * 256;
            bl = make_float4(bb[u], bb[64 + u], bb[128 + u], bb[192 + u]);
        }
    }
    __syncthreads();

    const u4v* hOwn   = (const u4v*)(&hL[layer][0]) + half * 4;
    const u4v* hBelow = (layer > 0) ? (const u4v*)(&hL[layer - 1][0]) + half * 4 : hOwn;

    // x preacts: wave 0 only, consume-then-reload 4-deep (R10 fix)
    const float4* xp = (const float4*)(xg + (size_t)b * T * 256) + u;
    float4 xb[4];
    xb[0] = xb[1] = xb[2] = xb[3] = make_float4(0.f, 0.f, 0.f, 0.f);
    if (wv == 0) {
#pragma unroll
        for (int k = 0; k < 4; k++) xb[k] = xp[(size_t)k * 64];
    }

    float* hout = Hout + (size_t)b * T * 64 + u;

#define FD(HP, WV, ACC) ACC = __builtin_amdgcn_fdot2(asH2(HP), asH2(WV), ACC, false)
#define QSTEP(HS, S, WI, WF, WG, WO) { u4v hp = (HS)[S];                      \
    FD(hp.x, WI.x, aI); FD(hp.y, WI.y, aI); FD(hp.z, WI.z, aI); FD(hp.w, WI.w, aI); \
    FD(hp.x, WF.x, aF); FD(hp.y, WF.y, aF); FD(hp.z, WF.z, aF); FD(hp.w, WF.w, aF); \
    FD(hp.x, WG.x, aG); FD(hp.y, WG.y, aG); FD(hp.z, WG.z, aG); FD(hp.w, WG.w, aG); \
    FD(hp.x, WO.x, aO); FD(hp.y, WO.y, aO); FD(hp.z, WO.z, aO); FD(hp.w, WO.w, aO); }

    int Tt = T + 4;   // pipeline drain
    for (int t4 = 0; t4 < Tt; t4 += 4) {
#pragma unroll
        for (int k = 0; k < 4; k++) {
            int tick = t4 + k;

            float aI, aF, aG, aO;
            if (wv == 0) {
                float4 x = xb[k];
                aI = x.x; aF = x.y; aG = x.z; aO = x.w;
                int tp = tick + 4; if (tp > T - 1) tp = T - 1;
                xb[k] = xp[(size_t)tp * 64];   // wait lands 4 ticks later
            } else {
                aI = aF = aG = aO = 0.f;
            }

            QSTEP(hOwn, 0, hI0, hF0, hG0, hO0)
            QSTEP(hOwn, 1, hI1, hF1, hG1, hO1)
            QSTEP(hOwn, 2, hI2, hF2, hG2, hO2)
            QSTEP(hOwn, 3, hI3, hF3, hG3, hO3)
            if (layer > 0) {
                QSTEP(hBelow, 0, xI0, xF0, xG0, xO0)
                QSTEP(hBelow, 1, xI1, xF1, xG1, xO1)
                QSTEP(hBelow, 2, xI2, xF2, xG2, xO2)
                QSTEP(hBelow, 3, xI3, xF3, xG3, xO3)
            }

            exch[wv][u] = make_float4(aI, aF, aG, aO);
            LDS_BARRIER();   // partials visible

            if (isRed) {
                int tcur = tick - layer;
                if ((unsigned)tcur < (unsigned)T) {
                    float4 p = exch[wv + 1][u];
                    float sI = aI + p.x + bl.x, sF = aF + p.y + bl.y;
                    float sG = aG + p.z + bl.z, sO = aO + p.w + bl.w;
                    c = sigmoidf_(sF) * c + sigmoidf_(sI) * tanhf_(sG);
                    float h = sigmoidf_(sO) * tanhf_(c);
                    hL[layer][u] = (_Float16)h;
                    if (layer == 2) hout[(size_t)tcur * 64] = h;
                }
            }
            LDS_BARRIER();   // h writes visible; WAR on exch protected
        }
    }
#undef FD
#undef QSTEP
}

// ---------------------------------------------------------------------------
// Hc[b, {max,mean,std(ddof=1)}, t] over hidden dim (64). One wave per (b,t).
// ---------------------------------------------------------------------------
__global__ __launch_bounds__(256) void stats_kernel(
    const float* __restrict__ H, float* __restrict__ Hc, int T)
{
    int wid = threadIdx.x >> 6, lane = threadIdx.x & 63;
    int bt = blockIdx.x * 4 + wid;
    int b = bt / T, t = bt - b * T;

    float x = H[(size_t)bt * 64 + lane];
    float mx = x, sm = x;
#pragma unroll
    for (int m = 32; m >= 1; m >>= 1) {
        mx = fmaxf(mx, __shfl_xor(mx, m));
        sm += __shfl_xor(sm, m);
    }
    float mean = sm * (1.0f / 64.0f);
    float d = x - mean;
    float ss = d * d;
#pragma unroll
    for (int m = 32; m >= 1; m >>= 1) ss += __shfl_xor(ss, m);
    float sd = sqrtf(ss * (1.0f / 63.0f));

    if (lane == 0) {
        float* o = Hc + (size_t)b * 3 * T;
        o[0 * T + t] = mx;
        o[1 * T + t] = mean;
        o[2 * T + t] = sd;
    }
}

// ---------------------------------------------------------------------------
// Middle conv/BN chain, single workgroup (1024 threads).
// ---------------------------------------------------------------------------
template <int CIN, int COUT, int MODE>
DEV void conv_bn_stage(const float* __restrict__ in, const float* __restrict__ w,
                       const float* __restrict__ bias, float* __restrict__ out,
                       float* __restrict__ gate, int T, int tid,
                       float* rs, float* rq, float* stm, float* sti)
{
    float lsum[COUT], lss[COUT];
#pragma unroll
    for (int oc = 0; oc < COUT; oc++) { lsum[oc] = 0.f; lss[oc] = 0.f; }

    for (int k = 0; k < 8; k++) {
        int p = tid + k * 1024;
        int b = p / T;
        int t = p - b * T;
        float acc[COUT];
#pragma unroll
        for (int oc = 0; oc < COUT; oc++) acc[oc] = bias[oc];
#pragma unroll
        for (int ic = 0; ic < CIN; ic++) {
            const float* row = in + ((size_t)b * CIN + ic) * T;
            float xv[11];
#pragma unroll
            for (int kk = 0; kk < 11; kk++) {
                int tt = t + kk - 5;
                xv[kk] = (tt >= 0 && tt < T) ? row[tt] : 0.f;
            }
#pragma unroll
            for (int oc = 0; oc < COUT; oc++) {
                const float* wr = w + ((size_t)oc * CIN + ic) * 11;
#pragma unroll
                for (int kk = 0; kk < 11; kk++) acc[oc] += xv[kk] * wr[kk];
            }
        }
#pragma unroll
        for (int oc = 0; oc < COUT; oc++) {
            out[((size_t)b * COUT + oc) * T + t] = acc[oc];
            lsum[oc] += acc[oc];
            lss[oc] += acc[oc] * acc[oc];
        }
    }
    __syncthreads();

    int lane = tid & 63, wid = tid >> 6;
#pragma unroll
    for (int oc = 0; oc < COUT; oc++) {
        float s = lsum[oc], qq = lss[oc];
#pragma unroll
        for (int m = 32; m >= 1; m >>= 1) {
            s += __shfl_xor(s, m);
            qq += __shfl_xor(qq, m);
        }
        if (lane == 0) { rs[wid] = s; rq[wid] = qq; }
        __syncthreads();
        if (tid == 0) {
            float S = 0.f, Q = 0.f;
            for (int i = 0; i < 16; i++) { S += rs[i]; Q += rq[i]; }
            float m_ = S / (float)(2 * T);
            float v = Q / (float)(2 * T) - m_ * m_;
            stm[oc] = m_;
            sti[oc] = rsqrtf(v + 1e-5f);
        }
        __syncthreads();
    }

    for (int k = 0; k < 8; k++) {
        int p = tid + k * 1024;
        int b = p / T;
        int t = p - b * T;
#pragma unroll
        for (int oc = 0; oc < COUT; oc++) {
            size_t idx = ((size_t)b * COUT + oc) * T + t;
            float v = (out[idx] - stm[oc]) * sti[oc];
            if (MODE == 0) out[idx] = fmaxf(v, 0.f);
            else           gate[p] = sigmoidf_(v);
        }
    }
    __syncthreads();
}

__global__ __launch_bounds__(1024) void middle_kernel(
    const float* __restrict__ Hc,
    const float* __restrict__ w1, const float* __restrict__ b1,
    const float* __restrict__ w2, const float* __restrict__ b2,
    const float* __restrict__ w3, const float* __restrict__ b3,
    const float* __restrict__ w4, const float* __restrict__ b4,
    float* __restrict__ bufA, float* __restrict__ bufB,
    float* __restrict__ gate, int T)
{
    __shared__ float rs[16], rq[16], stm[8], sti[8];
    int tid = threadIdx.x;
    conv_bn_stage<3, 3, 0>(Hc,   w1, b1, bufA, nullptr, T, tid, rs, rq, stm, sti);
    conv_bn_stage<3, 5, 0>(bufA, w2, b2, bufB, nullptr, T, tid, rs, rq, stm, sti);
    conv_bn_stage<5, 5, 0>(bufB, w3, b3, bufA, nullptr, T, tid, rs, rq, stm, sti);
    conv_bn_stage<5, 1, 1>(bufA, w4, b4, bufB, gate,    T, tid, rs, rq, stm, sti);
}

// ---------------------------------------------------------------------------
// Head: y = sigmoid(fc2(fc1(out2))). One wave per (b,t).
// ---------------------------------------------------------------------------
__global__ __launch_bounds__(256) void final_kernel(
    const float* __restrict__ out2, const float* __restrict__ fc1w,
    const float* __restrict__ fc1b, const float* __restrict__ fc2w,
    const float* __restrict__ fc2b, float* __restrict__ out, int T)
{
    int wid = threadIdx.x >> 6, lane = threadIdx.x & 63;
    int bt = blockIdx.x * 4 + wid;

    const float* o2 = out2 + (size_t)bt * 64;
    float acc = fc1b[lane];
    const float* wr = fc1w + (size_t)lane * 64;
#pragma unroll
    for (int k = 0; k < 64; k++) acc += o2[k] * wr[k];

    float p = acc * fc2w[lane];
#pragma unroll
    for (int m = 32; m >= 1; m >>= 1) p += __shfl_xor(p, m);

    if (lane == 0) out[bt] = sigmoidf_(p + fc2b[0]);
}

// ---------------------------------------------------------------------------
extern "C" void kernel_launch(void* const* d_in, const int* in_sizes, int n_in,
                              void* d_out, int out_size, void* d_ws, size_t ws_size,
                              hipStream_t stream)
{
    const float* data  = (const float*)d_in[0];
    const float* h01   = (const float*)d_in[1];
    const float* c01   = (const float*)d_in[2];
    const float* h02   = (const float*)d_in[3];
    const float* c02   = (const float*)d_in[4];
    const float* Wih0  = (const float*)d_in[5];
    const float* Wih12 = (const float*)d_in[6];
    const float* l1Whh = (const float*)d_in[7];
    const float* l1b   = (const float*)d_in[8];
    const float* l2Wih = (const float*)d_in[9];
    const float* l2Whh = (const float*)d_in[10];
    const float* l2b   = (const float*)d_in[11];
    const float* cw1 = (const float*)d_in[12]; const float* cb1 = (const float*)d_in[13];
    const float* cw2 = (const float*)d_in[14]; const float* cb2 = (const float*)d_in[15];
    const float* cw3 = (const float*)d_in[16]; const float* cb3 = (const float*)d_in[17];
    const float* cw4 = (const float*)d_in[18]; const float* cb4 = (const float*)d_in[19];
    const float* fc1w = (const float*)d_in[20]; const float* fc1b = (const float*)d_in[21];
    const float* fc2w = (const float*)d_in[22]; const float* fc2b = (const float*)d_in[23];
    float* out = (float*)d_out;

    const int T = in_sizes[0] / (2 * 40);   // 4096
    const int B = 2;

    float* ws   = (float*)d_ws;
    float* xg   = ws;                                // B*T*256
    float* seqA = xg   + (size_t)B * T * 256;        // B*T*64
    float* seqB = seqA + (size_t)B * T * 64;         // B*T*64
    float* Hc   = seqB + (size_t)B * T * 64;         // B*3*T
    float* bufA = Hc   + (size_t)B * 3 * T;          // B*5*T
    float* bufB = bufA + (size_t)B * 5 * T;          // B*5*T
    float* gate = bufB + (size_t)B * 5 * T;          // B*T
    unsigned* wP = (unsigned*)(gate + (size_t)B * T); // 10*8192 u32

    dim3 pg(B * (T / 16)), pb(256);

    pack_w<<<320, 256, 0, stream>>>(l1Whh, l2Whh, Wih12, l2Wih, wP);

    // ---- LSTM1: proj layer0 + pipelined 3-layer scan ----
    proj_kernel<<<pg, pb, 0, stream>>>(data, Wih0, l1b, nullptr, xg, 40, T);
    scan3_kernel<<<2, 384, 0, stream>>>(xg, wP, wP + 6 * 8192, l1b, h01, c01, seqA, T);

    // ---- temporal-attention gate ----
    stats_kernel<<<(2 * T) / 4, 256, 0, stream>>>(seqA, Hc, T);
    middle_kernel<<<1, 1024, 0, stream>>>(Hc, cw1, cb1, cw2, cb2, cw3, cb3, cw4, cb4,
                                          bufA, bufB, gate, T);

    // ---- LSTM2: proj layer0 (gate folded) + pipelined 3-layer scan ----
    proj_kernel<<<pg, pb, 0, stream>>>(seqA, l2Wih, l2b, gate, xg, 64, T);
    scan3_kernel<<<2, 384, 0, stream>>>(xg, wP + 3 * 8192, wP + 8 * 8192, l2b, h02, c02, seqB, T);

    // ---- head ----
    final_kernel<<<(2 * T) / 4, 256, 0, stream>>>(seqB, fc1w, fc1b, fc2w, fc2b, out, T);
}